// Round 2
// baseline (4098.107 us; speedup 1.0000x reference)
//
#include <hip/hip_runtime.h>

#define H 2048
#define I_DIM 4096
#define E_NUM 8
#define T_TOK 8192
#define SLOTS 16384

typedef __attribute__((ext_vector_type(8))) short bf16x8;
typedef __attribute__((ext_vector_type(4))) float f32x4;
typedef __attribute__((ext_vector_type(8))) unsigned short u16x8;

__device__ __forceinline__ unsigned short f2bf(float f) {
  union { float f; unsigned int u; } v; v.f = f;
  unsigned int r = v.u + 0x7fffu + ((v.u >> 16) & 1u);
  return (unsigned short)(r >> 16);
}

// ---------------- convert x (f32 -> bf16) ----------------
__global__ __launch_bounds__(256) void k_cvt_x(const float* __restrict__ x,
                                               unsigned short* __restrict__ xb) {
  size_t i = ((size_t)blockIdx.x * 256 + threadIdx.x) * 8;
  f32x4 a = *(const f32x4*)(x + i);
  f32x4 b = *(const f32x4*)(x + i + 4);
  u16x8 o;
#pragma unroll
  for (int j = 0; j < 4; ++j) { o[j] = f2bf(a[j]); o[4 + j] = f2bf(b[j]); }
  *(u16x8*)(xb + i) = o;
}

// ---------------- router ----------------
__global__ __launch_bounds__(256) void k_router(
    const float* __restrict__ x, const float* __restrict__ rw,
    int* __restrict__ tok_e, float* __restrict__ tok_w,
    int* __restrict__ counts, float* __restrict__ probs_sum, float* __restrict__ z_sum) {
  __shared__ __align__(16) float s_rw[E_NUM * H];
  int tid = threadIdx.x;
  for (int i = tid * 4; i < E_NUM * H; i += 256 * 4)
    *(f32x4*)&s_rw[i] = *(const f32x4*)&rw[i];
  __syncthreads();

  int lane = tid & 63;
  int t = blockIdx.x * 4 + (tid >> 6);
  const float* xr = x + (size_t)t * H;

  float acc[E_NUM];
#pragma unroll
  for (int e = 0; e < E_NUM; ++e) acc[e] = 0.f;
  for (int j = 0; j < H / 64; ++j) {
    int c = j * 64 + lane;
    float xv = xr[c];
#pragma unroll
    for (int e = 0; e < E_NUM; ++e) acc[e] = fmaf(xv, s_rw[e * H + c], acc[e]);
  }
#pragma unroll
  for (int e = 0; e < E_NUM; ++e) {
    float v = acc[e];
#pragma unroll
    for (int off = 32; off > 0; off >>= 1) v += __shfl_down(v, off, 64);
    acc[e] = v;
  }
  if (lane == 0) {
    int i0 = 0; float l0 = acc[0];
#pragma unroll
    for (int e = 1; e < E_NUM; ++e) if (acc[e] > l0) { l0 = acc[e]; i0 = e; }
    int i1 = -1; float l1 = -3.4e38f;
#pragma unroll
    for (int e = 0; e < E_NUM; ++e) if (e != i0 && acc[e] > l1) { l1 = acc[e]; i1 = e; }
    float w0 = 1.f / (1.f + expf(l1 - l0));
    tok_e[t * 2] = i0; tok_e[t * 2 + 1] = i1;
    tok_w[t * 2] = w0; tok_w[t * 2 + 1] = 1.f - w0;

    float s = 0.f; float p[E_NUM];
#pragma unroll
    for (int e = 0; e < E_NUM; ++e) { p[e] = expf(acc[e] - l0); s += p[e]; }
    float inv = 1.f / s;
#pragma unroll
    for (int e = 0; e < E_NUM; ++e) atomicAdd(&probs_sum[e], p[e] * inv);
    atomicAdd(z_sum, l0 + logf(s));
    atomicAdd(&counts[i0], 1);
    atomicAdd(&counts[i1], 1);
  }
}

// ---------------- finalize: offsets + loss ----------------
__global__ void k_finalize(const int* __restrict__ counts, int* __restrict__ offsets,
                           const float* __restrict__ probs_sum, const float* __restrict__ z_sum,
                           float* __restrict__ loss_out) {
  if (threadIdx.x == 0 && blockIdx.x == 0) {
    int off = 0; float aux = 0.f;
    for (int e = 0; e < E_NUM; ++e) {
      offsets[e] = off; off += counts[e];
      aux += ((float)counts[e] / (float)(T_TOK * 2)) * (probs_sum[e] / (float)T_TOK);
    }
    *loss_out = (float)E_NUM * aux * 0.01f + 0.001f * (*z_sum / (float)T_TOK);
  }
}

// ---------------- scatter tokens to expert slots ----------------
__global__ __launch_bounds__(256) void k_scatter(
    const int* __restrict__ tok_e, const float* __restrict__ tok_w,
    const int* __restrict__ offsets, int* __restrict__ fill,
    int* __restrict__ rows, float* __restrict__ wgt) {
  int t = blockIdx.x * 256 + threadIdx.x;
#pragma unroll
  for (int k = 0; k < 2; ++k) {
    int e = tok_e[t * 2 + k];
    int s = offsets[e] + atomicAdd(&fill[e], 1);
    rows[s] = t;
    wgt[s] = tok_w[t * 2 + k];
  }
}

// ---------------- GEMM1: gate+up + SwiGLU -> h (bf16) ----------------
// grid.x = 8 experts * 64 row-tiles (BM=128), grid.y = I/64 col tiles
__global__ __launch_bounds__(256) void k_gemm1(
    const unsigned short* __restrict__ xb,
    const float* __restrict__ gw, const float* __restrict__ uw,
    const int* __restrict__ counts, const int* __restrict__ offsets,
    const int* __restrict__ rows, unsigned short* __restrict__ h) {
  int e = blockIdx.x >> 6, rt = blockIdx.x & 63;
  int Te = counts[e];
  int r0 = rt * 128;
  if (r0 >= Te) return;
  int base = offsets[e];
  int ct = blockIdx.y;

  __shared__ __align__(16) unsigned short sA[128 * 64];
  __shared__ __align__(16) unsigned short sG[64 * 64];
  __shared__ __align__(16) unsigned short sU[64 * 64];

  int tid = threadIdx.x, lane = tid & 63, wv = tid >> 6;

  // A staging map: row ar = tid>>1, granules agb..agb+3
  int ar = tid >> 1;
  int agb = (tid & 1) * 4;
  int lr = r0 + ar; if (lr >= Te) lr = Te - 1;
  const unsigned short* asrc = xb + (size_t)rows[base + lr] * H + agb * 8;

  // B staging map: row br = tid>>2, granules bgb..bgb+1
  int br = tid >> 2;
  int bgb = (tid & 3) * 2;
  const float* gsrc = gw + ((size_t)e * I_DIM + (size_t)ct * 64 + br) * H + bgb * 8;
  const float* usrc = uw + ((size_t)e * I_DIM + (size_t)ct * 64 + br) * H + bgb * 8;

  f32x4 accg[2][4], accu[2][4];
#pragma unroll
  for (int m = 0; m < 2; ++m)
#pragma unroll
    for (int n = 0; n < 4; ++n) { accg[m][n] = (f32x4)0.f; accu[m][n] = (f32x4)0.f; }

  for (int k0 = 0; k0 < H; k0 += 64) {
    u16x8 av[4];
#pragma unroll
    for (int i = 0; i < 4; ++i) av[i] = *(const u16x8*)(asrc + k0 + i * 8);
    f32x4 gv[2][2], uv[2][2];
#pragma unroll
    for (int i = 0; i < 2; ++i) {
      gv[i][0] = *(const f32x4*)(gsrc + k0 + i * 8);
      gv[i][1] = *(const f32x4*)(gsrc + k0 + i * 8 + 4);
      uv[i][0] = *(const f32x4*)(usrc + k0 + i * 8);
      uv[i][1] = *(const f32x4*)(usrc + k0 + i * 8 + 4);
    }
    __syncthreads();
#pragma unroll
    for (int i = 0; i < 4; ++i)
      *(u16x8*)&sA[ar * 64 + ((agb + i) ^ (ar & 7)) * 8] = av[i];
#pragma unroll
    for (int i = 0; i < 2; ++i) {
      u16x8 tg, tu;
#pragma unroll
      for (int j = 0; j < 4; ++j) {
        tg[j] = f2bf(gv[i][0][j]); tg[4 + j] = f2bf(gv[i][1][j]);
        tu[j] = f2bf(uv[i][0][j]); tu[4 + j] = f2bf(uv[i][1][j]);
      }
      *(u16x8*)&sG[br * 64 + ((bgb + i) ^ (br & 7)) * 8] = tg;
      *(u16x8*)&sU[br * 64 + ((bgb + i) ^ (br & 7)) * 8] = tu;
    }
    __syncthreads();

#pragma unroll
    for (int kk = 0; kk < 2; ++kk) {
      bf16x8 af[2], gf[4], uf[4];
#pragma unroll
      for (int m = 0; m < 2; ++m) {
        int r = wv * 32 + m * 16 + (lane & 15);
        int g = (kk * 4 + (lane >> 4)) ^ (r & 7);
        af[m] = *(const bf16x8*)&sA[r * 64 + g * 8];
      }
#pragma unroll
      for (int n = 0; n < 4; ++n) {
        int r = n * 16 + (lane & 15);
        int g = (kk * 4 + (lane >> 4)) ^ (r & 7);
        gf[n] = *(const bf16x8*)&sG[r * 64 + g * 8];
        uf[n] = *(const bf16x8*)&sU[r * 64 + g * 8];
      }
#pragma unroll
      for (int m = 0; m < 2; ++m)
#pragma unroll
        for (int n = 0; n < 4; ++n) {
          accg[m][n] = __builtin_amdgcn_mfma_f32_16x16x32_bf16(af[m], gf[n], accg[m][n], 0, 0, 0);
          accu[m][n] = __builtin_amdgcn_mfma_f32_16x16x32_bf16(af[m], uf[n], accu[m][n], 0, 0, 0);
        }
    }
  }

  int cbase = ct * 64;
#pragma unroll
  for (int m = 0; m < 2; ++m)
#pragma unroll
    for (int j = 0; j < 4; ++j) {
      int lrow = wv * 32 + m * 16 + (lane >> 4) * 4 + j;
      if (r0 + lrow < Te) {
        unsigned short* hrow = h + (size_t)(base + r0 + lrow) * I_DIM + cbase + (lane & 15);
#pragma unroll
        for (int n = 0; n < 4; ++n) {
          float g = accg[m][n][j], u = accu[m][n][j];
          float hv = g / (1.f + expf(-g)) * u;
          hrow[n * 16] = f2bf(hv);
        }
      }
    }
}

// ---------------- GEMM2: down + weighted combine ----------------
// grid.x = 8 * 64 row-tiles (BM=128), grid.y = H/64
__global__ __launch_bounds__(256) void k_gemm2(
    const unsigned short* __restrict__ h, const float* __restrict__ dw,
    const int* __restrict__ counts, const int* __restrict__ offsets,
    const int* __restrict__ rows, const float* __restrict__ wgt,
    float* __restrict__ out) {
  int e = blockIdx.x >> 6, rt = blockIdx.x & 63;
  int Te = counts[e];
  int r0 = rt * 128;
  if (r0 >= Te) return;
  int base = offsets[e];
  int ct = blockIdx.y;

  __shared__ __align__(16) unsigned short sA[128 * 64];
  __shared__ __align__(16) unsigned short sB[64 * 64];

  int tid = threadIdx.x, lane = tid & 63, wv = tid >> 6;

  int ar = tid >> 1;
  int agb = (tid & 1) * 4;
  int lr = r0 + ar; if (lr >= Te) lr = Te - 1;
  const unsigned short* asrc = h + (size_t)(base + lr) * I_DIM + agb * 8;

  int br = tid >> 2;
  int bgb = (tid & 3) * 2;
  const float* bsrc = dw + ((size_t)e * H + (size_t)ct * 64 + br) * I_DIM + bgb * 8;

  f32x4 acc[2][4];
#pragma unroll
  for (int m = 0; m < 2; ++m)
#pragma unroll
    for (int n = 0; n < 4; ++n) acc[m][n] = (f32x4)0.f;

  for (int k0 = 0; k0 < I_DIM; k0 += 64) {
    u16x8 av[4];
#pragma unroll
    for (int i = 0; i < 4; ++i) av[i] = *(const u16x8*)(asrc + k0 + i * 8);
    f32x4 bv[2][2];
#pragma unroll
    for (int i = 0; i < 2; ++i) {
      bv[i][0] = *(const f32x4*)(bsrc + k0 + i * 8);
      bv[i][1] = *(const f32x4*)(bsrc + k0 + i * 8 + 4);
    }
    __syncthreads();
#pragma unroll
    for (int i = 0; i < 4; ++i)
      *(u16x8*)&sA[ar * 64 + ((agb + i) ^ (ar & 7)) * 8] = av[i];
#pragma unroll
    for (int i = 0; i < 2; ++i) {
      u16x8 tb;
#pragma unroll
      for (int j = 0; j < 4; ++j) { tb[j] = f2bf(bv[i][0][j]); tb[4 + j] = f2bf(bv[i][1][j]); }
      *(u16x8*)&sB[br * 64 + ((bgb + i) ^ (br & 7)) * 8] = tb;
    }
    __syncthreads();

#pragma unroll
    for (int kk = 0; kk < 2; ++kk) {
      bf16x8 af[2], bf[4];
#pragma unroll
      for (int m = 0; m < 2; ++m) {
        int r = wv * 32 + m * 16 + (lane & 15);
        int g = (kk * 4 + (lane >> 4)) ^ (r & 7);
        af[m] = *(const bf16x8*)&sA[r * 64 + g * 8];
      }
#pragma unroll
      for (int n = 0; n < 4; ++n) {
        int r = n * 16 + (lane & 15);
        int g = (kk * 4 + (lane >> 4)) ^ (r & 7);
        bf[n] = *(const bf16x8*)&sB[r * 64 + g * 8];
      }
#pragma unroll
      for (int m = 0; m < 2; ++m)
#pragma unroll
        for (int n = 0; n < 4; ++n)
          acc[m][n] = __builtin_amdgcn_mfma_f32_16x16x32_bf16(af[m], bf[n], acc[m][n], 0, 0, 0);
    }
  }

  int cbase = ct * 64;
#pragma unroll
  for (int m = 0; m < 2; ++m)
#pragma unroll
    for (int j = 0; j < 4; ++j) {
      int lrow = wv * 32 + m * 16 + (lane >> 4) * 4 + j;
      if (r0 + lrow < Te) {
        int slot = base + r0 + lrow;
        float w = wgt[slot];
        float* orow = out + (size_t)rows[slot] * H + cbase + (lane & 15);
#pragma unroll
        for (int n = 0; n < 4; ++n)
          atomicAdd(&orow[n * 16], acc[m][n][j] * w);
      }
    }
}

extern "C" void kernel_launch(void* const* d_in, const int* in_sizes, int n_in,
                              void* d_out, int out_size, void* d_ws, size_t ws_size,
                              hipStream_t stream) {
  const float* x  = (const float*)d_in[0];
  const float* rw = (const float*)d_in[1];
  const float* gw = (const float*)d_in[2];
  const float* uw = (const float*)d_in[3];
  const float* dw = (const float*)d_in[4];
  float* out = (float*)d_out;

  char* ws = (char*)d_ws;
  int*   counts    = (int*)(ws + 0);      // 8
  int*   fill      = (int*)(ws + 32);     // 8
  int*   offsets   = (int*)(ws + 64);     // 8
  float* probs_sum = (float*)(ws + 96);   // 8
  float* z_sum     = (float*)(ws + 128);  // 1
  int*   tok_e     = (int*)(ws + 256);
  float* tok_w     = (float*)(ws + 256 + 65536);
  int*   rows      = (int*)(ws + 256 + 131072);
  float* wgt       = (float*)(ws + 256 + 196608);
  unsigned short* xb = (unsigned short*)(ws + 256 + 262144);
  unsigned short* hb = (unsigned short*)(ws + 256 + 262144 + (size_t)T_TOK * H * 2);

  hipMemsetAsync(ws, 0, 256, stream);
  hipMemsetAsync(d_out, 0, (size_t)out_size * sizeof(float), stream);

  k_cvt_x<<<(T_TOK * H / 8) / 256, 256, 0, stream>>>(x, xb);
  k_router<<<T_TOK / 4, 256, 0, stream>>>(x, rw, tok_e, tok_w, counts, probs_sum, z_sum);
  k_finalize<<<1, 64, 0, stream>>>(counts, offsets, probs_sum, z_sum, out + (out_size - 1));
  k_scatter<<<T_TOK / 256, 256, 0, stream>>>(tok_e, tok_w, offsets, fill, rows, wgt);
  k_gemm1<<<dim3(E_NUM * 64, I_DIM / 64), 256, 0, stream>>>(xb, gw, uw, counts, offsets, rows, hb);
  k_gemm2<<<dim3(E_NUM * 64, H / 64), 256, 0, stream>>>(hb, dw, counts, offsets, rows, wgt, out);
}

// Round 3
// 2915.504 us; speedup vs baseline: 1.4056x; 1.4056x over previous
//
#include <hip/hip_runtime.h>

#define H 2048
#define I_DIM 4096
#define E_NUM 8
#define T_TOK 8192
#define SLOTS 16384
#define NTS 136   // max active row-tiles: sum_e ceil(Te/128) <= 16384/128 + 7 = 135

typedef __attribute__((ext_vector_type(8))) short bf16x8;
typedef __attribute__((ext_vector_type(4))) float f32x4;
typedef __attribute__((ext_vector_type(8))) unsigned short u16x8;

__device__ __forceinline__ unsigned short f2bf(float f) {
  union { float f; unsigned int u; } v; v.f = f;
  unsigned int r = v.u + 0x7fffu + ((v.u >> 16) & 1u);
  return (unsigned short)(r >> 16);
}

// ---------------- convert x (f32 -> bf16) ----------------
__global__ __launch_bounds__(256) void k_cvt_x(const float* __restrict__ x,
                                               unsigned short* __restrict__ xb) {
  size_t i = ((size_t)blockIdx.x * 256 + threadIdx.x) * 8;
  f32x4 a = *(const f32x4*)(x + i);
  f32x4 b = *(const f32x4*)(x + i + 4);
  u16x8 o;
#pragma unroll
  for (int j = 0; j < 4; ++j) { o[j] = f2bf(a[j]); o[4 + j] = f2bf(b[j]); }
  *(u16x8*)(xb + i) = o;
}

// ---------------- router ----------------
__global__ __launch_bounds__(256) void k_router(
    const float* __restrict__ x, const float* __restrict__ rw,
    int* __restrict__ tok_e, float* __restrict__ tok_w,
    int* __restrict__ counts, float* __restrict__ probs_sum, float* __restrict__ z_sum) {
  __shared__ __align__(16) float s_rw[E_NUM * H];
  int tid = threadIdx.x;
  for (int i = tid * 4; i < E_NUM * H; i += 256 * 4)
    *(f32x4*)&s_rw[i] = *(const f32x4*)&rw[i];
  __syncthreads();

  int lane = tid & 63;
  int t = blockIdx.x * 4 + (tid >> 6);
  const float* xr = x + (size_t)t * H;

  float acc[E_NUM];
#pragma unroll
  for (int e = 0; e < E_NUM; ++e) acc[e] = 0.f;
  for (int j = 0; j < H / 64; ++j) {
    int c = j * 64 + lane;
    float xv = xr[c];
#pragma unroll
    for (int e = 0; e < E_NUM; ++e) acc[e] = fmaf(xv, s_rw[e * H + c], acc[e]);
  }
#pragma unroll
  for (int e = 0; e < E_NUM; ++e) {
    float v = acc[e];
#pragma unroll
    for (int off = 32; off > 0; off >>= 1) v += __shfl_down(v, off, 64);
    acc[e] = v;
  }
  if (lane == 0) {
    int i0 = 0; float l0 = acc[0];
#pragma unroll
    for (int e = 1; e < E_NUM; ++e) if (acc[e] > l0) { l0 = acc[e]; i0 = e; }
    int i1 = -1; float l1 = -3.4e38f;
#pragma unroll
    for (int e = 0; e < E_NUM; ++e) if (e != i0 && acc[e] > l1) { l1 = acc[e]; i1 = e; }
    float w0 = 1.f / (1.f + expf(l1 - l0));
    tok_e[t * 2] = i0; tok_e[t * 2 + 1] = i1;
    tok_w[t * 2] = w0; tok_w[t * 2 + 1] = 1.f - w0;

    float s = 0.f; float p[E_NUM];
#pragma unroll
    for (int e = 0; e < E_NUM; ++e) { p[e] = expf(acc[e] - l0); s += p[e]; }
    float inv = 1.f / s;
#pragma unroll
    for (int e = 0; e < E_NUM; ++e) atomicAdd(&probs_sum[e], p[e] * inv);
    atomicAdd(z_sum, l0 + logf(s));
    atomicAdd(&counts[i0], 1);
    atomicAdd(&counts[i1], 1);
  }
}

// ---------------- finalize: offsets + loss + active tile list ----------------
__global__ void k_finalize(const int* __restrict__ counts, int* __restrict__ offsets,
                           const float* __restrict__ probs_sum, const float* __restrict__ z_sum,
                           float* __restrict__ loss_out,
                           int* __restrict__ n_tiles, int* __restrict__ tile_e,
                           int* __restrict__ tile_r0) {
  if (threadIdx.x == 0 && blockIdx.x == 0) {
    int off = 0; float aux = 0.f; int nt = 0;
    for (int e = 0; e < E_NUM; ++e) {
      offsets[e] = off; off += counts[e];
      aux += ((float)counts[e] / (float)(T_TOK * 2)) * (probs_sum[e] / (float)T_TOK);
      for (int r0 = 0; r0 < counts[e]; r0 += 128) {
        tile_e[nt] = e; tile_r0[nt] = r0; ++nt;
      }
    }
    *n_tiles = nt;
    *loss_out = (float)E_NUM * aux * 0.01f + 0.001f * (*z_sum / (float)T_TOK);
  }
}

// ---------------- scatter tokens to expert slots ----------------
__global__ __launch_bounds__(256) void k_scatter(
    const int* __restrict__ tok_e, const float* __restrict__ tok_w,
    const int* __restrict__ offsets, int* __restrict__ fill,
    int* __restrict__ rows, float* __restrict__ wgt) {
  int t = blockIdx.x * 256 + threadIdx.x;
#pragma unroll
  for (int k = 0; k < 2; ++k) {
    int e = tok_e[t * 2 + k];
    int s = offsets[e] + atomicAdd(&fill[e], 1);
    rows[s] = t;
    wgt[s] = tok_w[t * 2 + k];
  }
}

// ---------------- GEMM1: gate+up + SwiGLU -> h (bf16) ----------------
// grid = NTS x (I/64); XCD-chunked swizzle, ct-major so the ~16 blocks sharing
// one (e,ct) weight panel are consecutive within one XCD's chunk (L2 reuse).
__global__ __launch_bounds__(256) void k_gemm1(
    const unsigned short* __restrict__ xb,
    const float* __restrict__ gw, const float* __restrict__ uw,
    const int* __restrict__ counts, const int* __restrict__ offsets,
    const int* __restrict__ rows, unsigned short* __restrict__ h,
    const int* __restrict__ n_tiles, const int* __restrict__ tile_e,
    const int* __restrict__ tile_r0) {
  const int total = NTS * (I_DIM / 64);
  const int chunk = total >> 3;
  int orig = blockIdx.y * NTS + blockIdx.x;
  int L = (orig & 7) * chunk + (orig >> 3);
  int ct = L / NTS;
  int bxt = L - ct * NTS;
  if (bxt >= *n_tiles) return;
  int e = tile_e[bxt];
  int r0 = tile_r0[bxt];
  int Te = counts[e];
  int base = offsets[e];

  __shared__ __align__(16) unsigned short sA[128 * 64];
  __shared__ __align__(16) unsigned short sG[64 * 64];
  __shared__ __align__(16) unsigned short sU[64 * 64];

  int tid = threadIdx.x, lane = tid & 63, wv = tid >> 6;

  // A staging map: row ar = tid>>1, granules agb..agb+3
  int ar = tid >> 1;
  int agb = (tid & 1) * 4;
  int lr = r0 + ar; if (lr >= Te) lr = Te - 1;
  const unsigned short* asrc = xb + (size_t)rows[base + lr] * H + agb * 8;

  // B staging map: row br = tid>>2, granules bgb..bgb+1
  int br = tid >> 2;
  int bgb = (tid & 3) * 2;
  const float* gsrc = gw + ((size_t)e * I_DIM + (size_t)ct * 64 + br) * H + bgb * 8;
  const float* usrc = uw + ((size_t)e * I_DIM + (size_t)ct * 64 + br) * H + bgb * 8;

  f32x4 accg[2][4], accu[2][4];
#pragma unroll
  for (int m = 0; m < 2; ++m)
#pragma unroll
    for (int n = 0; n < 4; ++n) { accg[m][n] = (f32x4)0.f; accu[m][n] = (f32x4)0.f; }

  for (int k0 = 0; k0 < H; k0 += 64) {
    u16x8 av[4];
#pragma unroll
    for (int i = 0; i < 4; ++i) av[i] = *(const u16x8*)(asrc + k0 + i * 8);
    f32x4 gv[2][2], uv[2][2];
#pragma unroll
    for (int i = 0; i < 2; ++i) {
      gv[i][0] = *(const f32x4*)(gsrc + k0 + i * 8);
      gv[i][1] = *(const f32x4*)(gsrc + k0 + i * 8 + 4);
      uv[i][0] = *(const f32x4*)(usrc + k0 + i * 8);
      uv[i][1] = *(const f32x4*)(usrc + k0 + i * 8 + 4);
    }
    __syncthreads();
#pragma unroll
    for (int i = 0; i < 4; ++i)
      *(u16x8*)&sA[ar * 64 + ((agb + i) ^ (ar & 7)) * 8] = av[i];
#pragma unroll
    for (int i = 0; i < 2; ++i) {
      u16x8 tg, tu;
#pragma unroll
      for (int j = 0; j < 4; ++j) {
        tg[j] = f2bf(gv[i][0][j]); tg[4 + j] = f2bf(gv[i][1][j]);
        tu[j] = f2bf(uv[i][0][j]); tu[4 + j] = f2bf(uv[i][1][j]);
      }
      *(u16x8*)&sG[br * 64 + ((bgb + i) ^ (br & 7)) * 8] = tg;
      *(u16x8*)&sU[br * 64 + ((bgb + i) ^ (br & 7)) * 8] = tu;
    }
    __syncthreads();

#pragma unroll
    for (int kk = 0; kk < 2; ++kk) {
      bf16x8 af[2], gf[4], uf[4];
#pragma unroll
      for (int m = 0; m < 2; ++m) {
        int r = wv * 32 + m * 16 + (lane & 15);
        int g = (kk * 4 + (lane >> 4)) ^ (r & 7);
        af[m] = *(const bf16x8*)&sA[r * 64 + g * 8];
      }
#pragma unroll
      for (int n = 0; n < 4; ++n) {
        int r = n * 16 + (lane & 15);
        int g = (kk * 4 + (lane >> 4)) ^ (r & 7);
        gf[n] = *(const bf16x8*)&sG[r * 64 + g * 8];
        uf[n] = *(const bf16x8*)&sU[r * 64 + g * 8];
      }
#pragma unroll
      for (int m = 0; m < 2; ++m)
#pragma unroll
        for (int n = 0; n < 4; ++n) {
          accg[m][n] = __builtin_amdgcn_mfma_f32_16x16x32_bf16(af[m], gf[n], accg[m][n], 0, 0, 0);
          accu[m][n] = __builtin_amdgcn_mfma_f32_16x16x32_bf16(af[m], uf[n], accu[m][n], 0, 0, 0);
        }
    }
  }

  int cbase = ct * 64;
#pragma unroll
  for (int m = 0; m < 2; ++m)
#pragma unroll
    for (int j = 0; j < 4; ++j) {
      int lrow = wv * 32 + m * 16 + (lane >> 4) * 4 + j;
      if (r0 + lrow < Te) {
        unsigned short* hrow = h + (size_t)(base + r0 + lrow) * I_DIM + cbase + (lane & 15);
#pragma unroll
        for (int n = 0; n < 4; ++n) {
          float g = accg[m][n][j], u = accu[m][n][j];
          float hv = g / (1.f + expf(-g)) * u;
          hrow[n * 16] = f2bf(hv);
        }
      }
    }
}

// ---------------- GEMM2: down + weighted combine ----------------
// grid = NTS x (H/64); same XCD-chunked swizzle.
__global__ __launch_bounds__(256) void k_gemm2(
    const unsigned short* __restrict__ h, const float* __restrict__ dw,
    const int* __restrict__ counts, const int* __restrict__ offsets,
    const int* __restrict__ rows, const float* __restrict__ wgt,
    float* __restrict__ out,
    const int* __restrict__ n_tiles, const int* __restrict__ tile_e,
    const int* __restrict__ tile_r0) {
  const int total = NTS * (H / 64);
  const int chunk = total >> 3;
  int orig = blockIdx.y * NTS + blockIdx.x;
  int L = (orig & 7) * chunk + (orig >> 3);
  int ct = L / NTS;
  int bxt = L - ct * NTS;
  if (bxt >= *n_tiles) return;
  int e = tile_e[bxt];
  int r0 = tile_r0[bxt];
  int Te = counts[e];
  int base = offsets[e];

  __shared__ __align__(16) unsigned short sA[128 * 64];
  __shared__ __align__(16) unsigned short sB[64 * 64];

  int tid = threadIdx.x, lane = tid & 63, wv = tid >> 6;

  int ar = tid >> 1;
  int agb = (tid & 1) * 4;
  int lr = r0 + ar; if (lr >= Te) lr = Te - 1;
  const unsigned short* asrc = h + (size_t)(base + lr) * I_DIM + agb * 8;

  int br = tid >> 2;
  int bgb = (tid & 3) * 2;
  const float* bsrc = dw + ((size_t)e * H + (size_t)ct * 64 + br) * I_DIM + bgb * 8;

  f32x4 acc[2][4];
#pragma unroll
  for (int m = 0; m < 2; ++m)
#pragma unroll
    for (int n = 0; n < 4; ++n) acc[m][n] = (f32x4)0.f;

  for (int k0 = 0; k0 < I_DIM; k0 += 64) {
    u16x8 av[4];
#pragma unroll
    for (int i = 0; i < 4; ++i) av[i] = *(const u16x8*)(asrc + k0 + i * 8);
    f32x4 bv[2][2];
#pragma unroll
    for (int i = 0; i < 2; ++i) {
      bv[i][0] = *(const f32x4*)(bsrc + k0 + i * 8);
      bv[i][1] = *(const f32x4*)(bsrc + k0 + i * 8 + 4);
    }
    __syncthreads();
#pragma unroll
    for (int i = 0; i < 4; ++i)
      *(u16x8*)&sA[ar * 64 + ((agb + i) ^ (ar & 7)) * 8] = av[i];
#pragma unroll
    for (int i = 0; i < 2; ++i) {
      u16x8 tb;
#pragma unroll
      for (int j = 0; j < 4; ++j) { tb[j] = f2bf(bv[i][0][j]); tb[4 + j] = f2bf(bv[i][1][j]); }
      *(u16x8*)&sB[br * 64 + ((bgb + i) ^ (br & 7)) * 8] = tb;
    }
    __syncthreads();

#pragma unroll
    for (int kk = 0; kk < 2; ++kk) {
      bf16x8 af[2], bf[4];
#pragma unroll
      for (int m = 0; m < 2; ++m) {
        int r = wv * 32 + m * 16 + (lane & 15);
        int g = (kk * 4 + (lane >> 4)) ^ (r & 7);
        af[m] = *(const bf16x8*)&sA[r * 64 + g * 8];
      }
#pragma unroll
      for (int n = 0; n < 4; ++n) {
        int r = n * 16 + (lane & 15);
        int g = (kk * 4 + (lane >> 4)) ^ (r & 7);
        bf[n] = *(const bf16x8*)&sB[r * 64 + g * 8];
      }
#pragma unroll
      for (int m = 0; m < 2; ++m)
#pragma unroll
        for (int n = 0; n < 4; ++n)
          acc[m][n] = __builtin_amdgcn_mfma_f32_16x16x32_bf16(af[m], bf[n], acc[m][n], 0, 0, 0);
    }
  }

  int cbase = ct * 64;
#pragma unroll
  for (int m = 0; m < 2; ++m)
#pragma unroll
    for (int j = 0; j < 4; ++j) {
      int lrow = wv * 32 + m * 16 + (lane >> 4) * 4 + j;
      if (r0 + lrow < Te) {
        int slot = base + r0 + lrow;
        float w = wgt[slot];
        float* orow = out + (size_t)rows[slot] * H + cbase + (lane & 15);
#pragma unroll
        for (int n = 0; n < 4; ++n)
          atomicAdd(&orow[n * 16], acc[m][n][j] * w);
      }
    }
}

extern "C" void kernel_launch(void* const* d_in, const int* in_sizes, int n_in,
                              void* d_out, int out_size, void* d_ws, size_t ws_size,
                              hipStream_t stream) {
  const float* x  = (const float*)d_in[0];
  const float* rw = (const float*)d_in[1];
  const float* gw = (const float*)d_in[2];
  const float* uw = (const float*)d_in[3];
  const float* dw = (const float*)d_in[4];
  float* out = (float*)d_out;

  char* ws = (char*)d_ws;
  int*   counts    = (int*)(ws + 0);      // 8
  int*   fill      = (int*)(ws + 32);     // 8
  int*   offsets   = (int*)(ws + 64);     // 8
  float* probs_sum = (float*)(ws + 96);   // 8
  float* z_sum     = (float*)(ws + 128);  // 1
  int*   n_tiles   = (int*)(ws + 132);    // 1
  int*   tile_e    = (int*)(ws + 256);    // 512 ints
  int*   tile_r0   = (int*)(ws + 2304);   // 512 ints
  int*   tok_e     = (int*)(ws + 8192);
  float* tok_w     = (float*)(ws + 8192 + 65536);
  int*   rows      = (int*)(ws + 8192 + 131072);
  float* wgt       = (float*)(ws + 8192 + 196608);
  unsigned short* xb = (unsigned short*)(ws + 8192 + 262144);
  unsigned short* hb = (unsigned short*)(ws + 8192 + 262144 + (size_t)T_TOK * H * 2);

  hipMemsetAsync(ws, 0, 256, stream);
  hipMemsetAsync(d_out, 0, (size_t)out_size * sizeof(float), stream);

  k_cvt_x<<<(T_TOK * H / 8) / 256, 256, 0, stream>>>(x, xb);
  k_router<<<T_TOK / 4, 256, 0, stream>>>(x, rw, tok_e, tok_w, counts, probs_sum, z_sum);
  k_finalize<<<1, 64, 0, stream>>>(counts, offsets, probs_sum, z_sum, out + (out_size - 1),
                                   n_tiles, tile_e, tile_r0);
  k_scatter<<<T_TOK / 256, 256, 0, stream>>>(tok_e, tok_w, offsets, fill, rows, wgt);
  k_gemm1<<<dim3(NTS, I_DIM / 64), 256, 0, stream>>>(xb, gw, uw, counts, offsets, rows, hb,
                                                     n_tiles, tile_e, tile_r0);
  k_gemm2<<<dim3(NTS, H / 64), 256, 0, stream>>>(hb, dw, counts, offsets, rows, wgt, out,
                                                 n_tiles, tile_e, tile_r0);
}

// Round 4
// 2231.145 us; speedup vs baseline: 1.8368x; 1.3067x over previous
//
#include <hip/hip_runtime.h>

#define H 2048
#define I_DIM 4096
#define E_NUM 8
#define T_TOK 8192
#define SLOTS 16384
#define NTS 136   // max active row-tiles: sum_e ceil(Te/128) <= 128 + 7 = 135

typedef __attribute__((ext_vector_type(8))) short bf16x8;
typedef __attribute__((ext_vector_type(4))) float f32x4;
typedef __attribute__((ext_vector_type(8))) unsigned short u16x8;

__device__ __forceinline__ unsigned short f2bf(float f) {
  union { float f; unsigned int u; } v; v.f = f;
  unsigned int r = v.u + 0x7fffu + ((v.u >> 16) & 1u);
  return (unsigned short)(r >> 16);
}

// async global->LDS, 16B per lane; LDS dest is wave-uniform base + lane*16
__device__ __forceinline__ void gload16(const unsigned short* g, unsigned short* l) {
  __builtin_amdgcn_global_load_lds(
      (const __attribute__((address_space(1))) unsigned int*)g,
      (__attribute__((address_space(3))) unsigned int*)l, 16, 0, 0);
}

// ---------------- generic f32 -> bf16 convert ----------------
__global__ __launch_bounds__(256) void k_cvt(const float* __restrict__ x,
                                             unsigned short* __restrict__ xb) {
  size_t i = ((size_t)blockIdx.x * 256 + threadIdx.x) * 8;
  f32x4 a = *(const f32x4*)(x + i);
  f32x4 b = *(const f32x4*)(x + i + 4);
  u16x8 o;
#pragma unroll
  for (int j = 0; j < 4; ++j) { o[j] = f2bf(a[j]); o[4 + j] = f2bf(b[j]); }
  *(u16x8*)(xb + i) = o;
}

// ---------------- router ----------------
__global__ __launch_bounds__(256) void k_router(
    const float* __restrict__ x, const float* __restrict__ rw,
    int* __restrict__ tok_e, float* __restrict__ tok_w,
    int* __restrict__ counts, float* __restrict__ probs_sum, float* __restrict__ z_sum) {
  __shared__ __align__(16) float s_rw[E_NUM * H];
  int tid = threadIdx.x;
  for (int i = tid * 4; i < E_NUM * H; i += 256 * 4)
    *(f32x4*)&s_rw[i] = *(const f32x4*)&rw[i];
  __syncthreads();

  int lane = tid & 63;
  int t = blockIdx.x * 4 + (tid >> 6);
  const float* xr = x + (size_t)t * H;

  float acc[E_NUM];
#pragma unroll
  for (int e = 0; e < E_NUM; ++e) acc[e] = 0.f;
  for (int j = 0; j < H / 64; ++j) {
    int c = j * 64 + lane;
    float xv = xr[c];
#pragma unroll
    for (int e = 0; e < E_NUM; ++e) acc[e] = fmaf(xv, s_rw[e * H + c], acc[e]);
  }
#pragma unroll
  for (int e = 0; e < E_NUM; ++e) {
    float v = acc[e];
#pragma unroll
    for (int off = 32; off > 0; off >>= 1) v += __shfl_down(v, off, 64);
    acc[e] = v;
  }
  if (lane == 0) {
    int i0 = 0; float l0 = acc[0];
#pragma unroll
    for (int e = 1; e < E_NUM; ++e) if (acc[e] > l0) { l0 = acc[e]; i0 = e; }
    int i1 = -1; float l1 = -3.4e38f;
#pragma unroll
    for (int e = 0; e < E_NUM; ++e) if (e != i0 && acc[e] > l1) { l1 = acc[e]; i1 = e; }
    float w0 = 1.f / (1.f + expf(l1 - l0));
    tok_e[t * 2] = i0; tok_e[t * 2 + 1] = i1;
    tok_w[t * 2] = w0; tok_w[t * 2 + 1] = 1.f - w0;

    float s = 0.f; float p[E_NUM];
#pragma unroll
    for (int e = 0; e < E_NUM; ++e) { p[e] = expf(acc[e] - l0); s += p[e]; }
    float inv = 1.f / s;
#pragma unroll
    for (int e = 0; e < E_NUM; ++e) atomicAdd(&probs_sum[e], p[e] * inv);
    atomicAdd(z_sum, l0 + logf(s));
    atomicAdd(&counts[i0], 1);
    atomicAdd(&counts[i1], 1);
  }
}

// ---------------- finalize: offsets + loss + active tile list ----------------
__global__ void k_finalize(const int* __restrict__ counts, int* __restrict__ offsets,
                           const float* __restrict__ probs_sum, const float* __restrict__ z_sum,
                           float* __restrict__ loss_out,
                           int* __restrict__ n_tiles, int* __restrict__ tile_e,
                           int* __restrict__ tile_r0) {
  if (threadIdx.x == 0 && blockIdx.x == 0) {
    int off = 0; float aux = 0.f; int nt = 0;
    for (int e = 0; e < E_NUM; ++e) {
      offsets[e] = off; off += counts[e];
      aux += ((float)counts[e] / (float)(T_TOK * 2)) * (probs_sum[e] / (float)T_TOK);
      for (int r0 = 0; r0 < counts[e]; r0 += 128) {
        tile_e[nt] = e; tile_r0[nt] = r0; ++nt;
      }
    }
    *n_tiles = nt;
    *loss_out = (float)E_NUM * aux * 0.01f + 0.001f * (*z_sum / (float)T_TOK);
  }
}

// ---------------- scatter tokens to expert slots ----------------
__global__ __launch_bounds__(256) void k_scatter(
    const int* __restrict__ tok_e, const float* __restrict__ tok_w,
    const int* __restrict__ offsets, int* __restrict__ fill,
    int* __restrict__ rows, float* __restrict__ wgt) {
  int t = blockIdx.x * 256 + threadIdx.x;
#pragma unroll
  for (int k = 0; k < 2; ++k) {
    int e = tok_e[t * 2 + k];
    int s = offsets[e] + atomicAdd(&fill[e], 1);
    rows[s] = t;
    wgt[s] = tok_w[t * 2 + k];
  }
}

// ---------------- GEMM1: gate+up + SwiGLU -> h (bf16) ----------------
// grid = NTS x 64 (ct over I/64); XCD-chunked, ct-major swizzle.
// Block tile 128 rows x 64 cols of BOTH gate and up. 4 waves in 2x2:
// wave = 64 rows x 32 cols of each matrix, acc 4x2 per matrix.
__global__ __launch_bounds__(256, 2) void k_gemm1(
    const unsigned short* __restrict__ xb,
    const unsigned short* __restrict__ gwb, const unsigned short* __restrict__ uwb,
    const int* __restrict__ counts, const int* __restrict__ offsets,
    const int* __restrict__ rows, unsigned short* __restrict__ h,
    const int* __restrict__ n_tiles, const int* __restrict__ tile_e,
    const int* __restrict__ tile_r0) {
  const int total = NTS * (I_DIM / 64);
  const int chunk = total >> 3;
  int orig = blockIdx.y * NTS + blockIdx.x;
  int L = (orig & 7) * chunk + (orig >> 3);
  int ct = L / NTS;
  int bxt = L - ct * NTS;
  if (bxt >= *n_tiles) return;
  int e = tile_e[bxt];
  int r0 = tile_r0[bxt];
  int Te = counts[e];
  int base = offsets[e];

  __shared__ __align__(16) unsigned short sA[128 * 64];
  __shared__ __align__(16) unsigned short sG[64 * 64];
  __shared__ __align__(16) unsigned short sU[64 * 64];

  int tid = threadIdx.x, lane = tid & 63, wv = tid >> 6;
  int wr = wv >> 1, wc = wv & 1;

  // pre-swizzled global granule so linear LDS write == swizzled content
  int gsg = ((lane & 7) ^ (lane >> 3)) * 8;

  // A: 16 wave-instrs total, 4 per wave; instr i covers rows 32*wv+8*i .. +7
  const unsigned short* a_src[4];
  unsigned short* a_dst[4];
#pragma unroll
  for (int i = 0; i < 4; ++i) {
    int r = 32 * wv + 8 * i + (lane >> 3);
    int lr = r0 + r; if (lr >= Te) lr = Te - 1;
    a_src[i] = xb + (size_t)rows[base + lr] * H + gsg;
    a_dst[i] = sA + (32 * wv + 8 * i) * 64;
  }
  // G/U: 8 wave-instrs each, 2 per wave
  const unsigned short* g_src[2]; const unsigned short* u_src[2];
  unsigned short* g_dst[2]; unsigned short* u_dst[2];
#pragma unroll
  for (int j = 0; j < 2; ++j) {
    int r = 16 * wv + 8 * j + (lane >> 3);
    size_t wrow = ((size_t)e * I_DIM + (size_t)ct * 64 + r) * H + gsg;
    g_src[j] = gwb + wrow;
    u_src[j] = uwb + wrow;
    g_dst[j] = sG + (16 * wv + 8 * j) * 64;
    u_dst[j] = sU + (16 * wv + 8 * j) * 64;
  }

  f32x4 accg[4][2], accu[4][2];
#pragma unroll
  for (int m = 0; m < 4; ++m)
#pragma unroll
    for (int n = 0; n < 2; ++n) { accg[m][n] = (f32x4)0.f; accu[m][n] = (f32x4)0.f; }

  for (int k0 = 0; k0 < H; k0 += 64) {
#pragma unroll
    for (int i = 0; i < 4; ++i) gload16(a_src[i] + k0, a_dst[i]);
#pragma unroll
    for (int j = 0; j < 2; ++j) gload16(g_src[j] + k0, g_dst[j]);
#pragma unroll
    for (int j = 0; j < 2; ++j) gload16(u_src[j] + k0, u_dst[j]);
    __syncthreads();   // drains vmcnt -> LDS data ready

#pragma unroll
    for (int kk = 0; kk < 2; ++kk) {
      bf16x8 af[4], gf[2], uf[2];
#pragma unroll
      for (int m = 0; m < 4; ++m) {
        int r = 64 * wr + m * 16 + (lane & 15);
        int g = (kk * 4 + (lane >> 4)) ^ (r & 7);
        af[m] = *(const bf16x8*)&sA[r * 64 + g * 8];
      }
#pragma unroll
      for (int n = 0; n < 2; ++n) {
        int r = 32 * wc + n * 16 + (lane & 15);
        int g = (kk * 4 + (lane >> 4)) ^ (r & 7);
        gf[n] = *(const bf16x8*)&sG[r * 64 + g * 8];
        uf[n] = *(const bf16x8*)&sU[r * 64 + g * 8];
      }
#pragma unroll
      for (int m = 0; m < 4; ++m)
#pragma unroll
        for (int n = 0; n < 2; ++n) {
          accg[m][n] = __builtin_amdgcn_mfma_f32_16x16x32_bf16(af[m], gf[n], accg[m][n], 0, 0, 0);
          accu[m][n] = __builtin_amdgcn_mfma_f32_16x16x32_bf16(af[m], uf[n], accu[m][n], 0, 0, 0);
        }
    }
    __syncthreads();   // protect LDS from next iteration's writes
  }

  int cbase = ct * 64 + wc * 32;
#pragma unroll
  for (int m = 0; m < 4; ++m)
#pragma unroll
    for (int j = 0; j < 4; ++j) {
      int lrow = 64 * wr + m * 16 + (lane >> 4) * 4 + j;
      if (r0 + lrow < Te) {
        unsigned short* hrow = h + (size_t)(base + r0 + lrow) * I_DIM + cbase + (lane & 15);
#pragma unroll
        for (int n = 0; n < 2; ++n) {
          float g = accg[m][n][j], u = accu[m][n][j];
          float hv = g / (1.f + expf(-g)) * u;
          hrow[n * 16] = f2bf(hv);
        }
      }
    }
}

// ---------------- GEMM2: down + weighted combine ----------------
// grid = NTS x 16 (ct over H/128); block tile 128 x 128, wave 64x64, acc 4x4.
__global__ __launch_bounds__(256, 2) void k_gemm2(
    const unsigned short* __restrict__ h, const unsigned short* __restrict__ dwb,
    const int* __restrict__ counts, const int* __restrict__ offsets,
    const int* __restrict__ rows, const float* __restrict__ wgt,
    float* __restrict__ out,
    const int* __restrict__ n_tiles, const int* __restrict__ tile_e,
    const int* __restrict__ tile_r0) {
  const int total = NTS * (H / 128);
  const int chunk = total >> 3;
  int orig = blockIdx.y * NTS + blockIdx.x;
  int L = (orig & 7) * chunk + (orig >> 3);
  int ct = L / NTS;
  int bxt = L - ct * NTS;
  if (bxt >= *n_tiles) return;
  int e = tile_e[bxt];
  int r0 = tile_r0[bxt];
  int Te = counts[e];
  int base = offsets[e];

  __shared__ __align__(16) unsigned short sA[128 * 64];
  __shared__ __align__(16) unsigned short sB[128 * 64];

  int tid = threadIdx.x, lane = tid & 63, wv = tid >> 6;
  int wr = wv >> 1, wc = wv & 1;

  int gsg = ((lane & 7) ^ (lane >> 3)) * 8;

  const unsigned short* a_src[4];
  unsigned short* a_dst[4];
#pragma unroll
  for (int i = 0; i < 4; ++i) {
    int r = 32 * wv + 8 * i + (lane >> 3);
    int lr = r0 + r; if (lr >= Te) lr = Te - 1;
    a_src[i] = h + (size_t)(base + lr) * I_DIM + gsg;
    a_dst[i] = sA + (32 * wv + 8 * i) * 64;
  }
  const unsigned short* b_src[4];
  unsigned short* b_dst[4];
#pragma unroll
  for (int i = 0; i < 4; ++i) {
    int r = 32 * wv + 8 * i + (lane >> 3);
    b_src[i] = dwb + ((size_t)e * H + (size_t)ct * 128 + r) * I_DIM + gsg;
    b_dst[i] = sB + (32 * wv + 8 * i) * 64;
  }

  f32x4 acc[4][4];
#pragma unroll
  for (int m = 0; m < 4; ++m)
#pragma unroll
    for (int n = 0; n < 4; ++n) acc[m][n] = (f32x4)0.f;

  for (int k0 = 0; k0 < I_DIM; k0 += 64) {
#pragma unroll
    for (int i = 0; i < 4; ++i) gload16(a_src[i] + k0, a_dst[i]);
#pragma unroll
    for (int i = 0; i < 4; ++i) gload16(b_src[i] + k0, b_dst[i]);
    __syncthreads();

#pragma unroll
    for (int kk = 0; kk < 2; ++kk) {
      bf16x8 af[4], bf[4];
#pragma unroll
      for (int m = 0; m < 4; ++m) {
        int r = 64 * wr + m * 16 + (lane & 15);
        int g = (kk * 4 + (lane >> 4)) ^ (r & 7);
        af[m] = *(const bf16x8*)&sA[r * 64 + g * 8];
      }
#pragma unroll
      for (int n = 0; n < 4; ++n) {
        int r = 64 * wc + n * 16 + (lane & 15);
        int g = (kk * 4 + (lane >> 4)) ^ (r & 7);
        bf[n] = *(const bf16x8*)&sB[r * 64 + g * 8];
      }
#pragma unroll
      for (int m = 0; m < 4; ++m)
#pragma unroll
        for (int n = 0; n < 4; ++n)
          acc[m][n] = __builtin_amdgcn_mfma_f32_16x16x32_bf16(af[m], bf[n], acc[m][n], 0, 0, 0);
    }
    __syncthreads();
  }

  int cbase = ct * 128 + wc * 64;
#pragma unroll
  for (int m = 0; m < 4; ++m)
#pragma unroll
    for (int j = 0; j < 4; ++j) {
      int lrow = 64 * wr + m * 16 + (lane >> 4) * 4 + j;
      if (r0 + lrow < Te) {
        int slot = base + r0 + lrow;
        float w = wgt[slot];
        float* orow = out + (size_t)rows[slot] * H + cbase + (lane & 15);
#pragma unroll
        for (int n = 0; n < 4; ++n)
          atomicAdd(&orow[n * 16], acc[m][n][j] * w);
      }
    }
}

extern "C" void kernel_launch(void* const* d_in, const int* in_sizes, int n_in,
                              void* d_out, int out_size, void* d_ws, size_t ws_size,
                              hipStream_t stream) {
  const float* x  = (const float*)d_in[0];
  const float* rw = (const float*)d_in[1];
  const float* gw = (const float*)d_in[2];
  const float* uw = (const float*)d_in[3];
  const float* dw = (const float*)d_in[4];
  float* out = (float*)d_out;

  char* ws = (char*)d_ws;
  int*   counts    = (int*)(ws + 0);      // 8
  int*   fill      = (int*)(ws + 32);     // 8
  int*   offsets   = (int*)(ws + 64);     // 8
  float* probs_sum = (float*)(ws + 96);   // 8
  float* z_sum     = (float*)(ws + 128);  // 1
  int*   n_tiles   = (int*)(ws + 132);    // 1
  int*   tile_e    = (int*)(ws + 256);    // <=512 ints
  int*   tile_r0   = (int*)(ws + 2304);
  int*   tok_e     = (int*)(ws + 8192);
  float* tok_w     = (float*)(ws + 8192 + 65536);
  int*   rows      = (int*)(ws + 8192 + 131072);
  float* wgt       = (float*)(ws + 8192 + 196608);
  size_t off = 8192 + 262144;
  unsigned short* xb  = (unsigned short*)(ws + off); off += (size_t)T_TOK * H * 2;
  unsigned short* hb  = (unsigned short*)(ws + off); off += (size_t)SLOTS * I_DIM * 2;
  unsigned short* gwb = (unsigned short*)(ws + off); off += (size_t)E_NUM * I_DIM * H * 2;
  unsigned short* uwb = (unsigned short*)(ws + off); off += (size_t)E_NUM * I_DIM * H * 2;
  unsigned short* dwb = (unsigned short*)(ws + off); off += (size_t)E_NUM * H * I_DIM * 2;

  hipMemsetAsync(ws, 0, 256, stream);
  hipMemsetAsync(d_out, 0, (size_t)out_size * sizeof(float), stream);

  const int WN = E_NUM * I_DIM * H;  // 67.1M elements per weight tensor
  k_cvt<<<(T_TOK * H / 8) / 256, 256, 0, stream>>>(x, xb);
  k_cvt<<<(WN / 8) / 256, 256, 0, stream>>>(gw, gwb);
  k_cvt<<<(WN / 8) / 256, 256, 0, stream>>>(uw, uwb);
  k_cvt<<<(WN / 8) / 256, 256, 0, stream>>>(dw, dwb);
  k_router<<<T_TOK / 4, 256, 0, stream>>>(x, rw, tok_e, tok_w, counts, probs_sum, z_sum);
  k_finalize<<<1, 64, 0, stream>>>(counts, offsets, probs_sum, z_sum, out + (out_size - 1),
                                   n_tiles, tile_e, tile_r0);
  k_scatter<<<T_TOK / 256, 256, 0, stream>>>(tok_e, tok_w, offsets, fill, rows, wgt);
  k_gemm1<<<dim3(NTS, I_DIM / 64), 256, 0, stream>>>(xb, gwb, uwb, counts, offsets, rows, hb,
                                                     n_tiles, tile_e, tile_r0);
  k_gemm2<<<dim3(NTS, H / 128), 256, 0, stream>>>(hb, dwb, counts, offsets, rows, wgt, out,
                                                  n_tiles, tile_e, tile_r0);
}

// Round 5
// 1493.694 us; speedup vs baseline: 2.7436x; 1.4937x over previous
//
#include <hip/hip_runtime.h>

#define H 2048
#define I_DIM 4096
#define E_NUM 8
#define T_TOK 8192
#define SLOTS 16384
#define NTS 136   // max active row-tiles: sum_e ceil(Te/128) <= 128 + 7 = 135

typedef __attribute__((ext_vector_type(8))) short bf16x8;
typedef __attribute__((ext_vector_type(4))) float f32x4;
typedef __attribute__((ext_vector_type(8))) unsigned short u16x8;

__device__ __forceinline__ unsigned short f2bf(float f) {
  union { float f; unsigned int u; } v; v.f = f;
  unsigned int r = v.u + 0x7fffu + ((v.u >> 16) & 1u);
  return (unsigned short)(r >> 16);
}

// async global->LDS, 16B per lane; LDS dest is wave-uniform base + lane*16
__device__ __forceinline__ void gload16(const unsigned short* g, unsigned short* l) {
  __builtin_amdgcn_global_load_lds(
      (const __attribute__((address_space(1))) unsigned int*)g,
      (__attribute__((address_space(3))) unsigned int*)l, 16, 0, 0);
}

// ---------------- generic f32 -> bf16 convert ----------------
__global__ __launch_bounds__(256) void k_cvt(const float* __restrict__ x,
                                             unsigned short* __restrict__ xb) {
  size_t i = ((size_t)blockIdx.x * 256 + threadIdx.x) * 8;
  f32x4 a = *(const f32x4*)(x + i);
  f32x4 b = *(const f32x4*)(x + i + 4);
  u16x8 o;
#pragma unroll
  for (int j = 0; j < 4; ++j) { o[j] = f2bf(a[j]); o[4 + j] = f2bf(b[j]); }
  *(u16x8*)(xb + i) = o;
}

// ---------------- router ----------------
// 256 blocks x 32 tokens. Block-local LDS accumulation of the loss statistics;
// ONE global atomicAdd per counter per block (was ~17 per token -> 110k
// serialized same-address atomics = 860us. Guideline 12.)
__global__ __launch_bounds__(256) void k_router(
    const float* __restrict__ x, const float* __restrict__ rw,
    int* __restrict__ tok_e, float* __restrict__ tok_w,
    int* __restrict__ counts, float* __restrict__ probs_sum, float* __restrict__ z_sum) {
  __shared__ __align__(16) float s_rw[E_NUM * H];
  __shared__ float s_probs[E_NUM];
  __shared__ float s_z;
  __shared__ int s_cnt[E_NUM];
  int tid = threadIdx.x;
  if (tid < E_NUM) { s_probs[tid] = 0.f; s_cnt[tid] = 0; }
  if (tid == 0) s_z = 0.f;
  for (int i = tid * 4; i < E_NUM * H; i += 256 * 4)
    *(f32x4*)&s_rw[i] = *(const f32x4*)&rw[i];
  __syncthreads();

  int lane = tid & 63, wv = tid >> 6;

  for (int it = 0; it < 8; ++it) {
    int t = blockIdx.x * 32 + wv * 8 + it;
    const float* xr = x + (size_t)t * H;

    float acc[E_NUM];
#pragma unroll
    for (int e = 0; e < E_NUM; ++e) acc[e] = 0.f;
    for (int j = 0; j < H / 64; ++j) {
      int c = j * 64 + lane;
      float xv = xr[c];
#pragma unroll
      for (int e = 0; e < E_NUM; ++e) acc[e] = fmaf(xv, s_rw[e * H + c], acc[e]);
    }
#pragma unroll
    for (int e = 0; e < E_NUM; ++e) {
      float v = acc[e];
#pragma unroll
      for (int off = 32; off > 0; off >>= 1) v += __shfl_down(v, off, 64);
      acc[e] = v;
    }
    if (lane == 0) {
      int i0 = 0; float l0 = acc[0];
#pragma unroll
      for (int e = 1; e < E_NUM; ++e) if (acc[e] > l0) { l0 = acc[e]; i0 = e; }
      int i1 = -1; float l1 = -3.4e38f;
#pragma unroll
      for (int e = 0; e < E_NUM; ++e) if (e != i0 && acc[e] > l1) { l1 = acc[e]; i1 = e; }
      float w0 = 1.f / (1.f + expf(l1 - l0));
      tok_e[t * 2] = i0; tok_e[t * 2 + 1] = i1;
      tok_w[t * 2] = w0; tok_w[t * 2 + 1] = 1.f - w0;

      float s = 0.f; float p[E_NUM];
#pragma unroll
      for (int e = 0; e < E_NUM; ++e) { p[e] = expf(acc[e] - l0); s += p[e]; }
      float inv = 1.f / s;
#pragma unroll
      for (int e = 0; e < E_NUM; ++e) atomicAdd(&s_probs[e], p[e] * inv);
      atomicAdd(&s_z, l0 + logf(s));
      atomicAdd(&s_cnt[i0], 1);
      atomicAdd(&s_cnt[i1], 1);
    }
  }
  __syncthreads();
  if (tid < E_NUM) {
    atomicAdd(&probs_sum[tid], s_probs[tid]);
    atomicAdd(&counts[tid], s_cnt[tid]);
  }
  if (tid == E_NUM) atomicAdd(z_sum, s_z);
}

// ---------------- finalize: offsets + loss + active tile list ----------------
__global__ void k_finalize(const int* __restrict__ counts, int* __restrict__ offsets,
                           const float* __restrict__ probs_sum, const float* __restrict__ z_sum,
                           float* __restrict__ loss_out,
                           int* __restrict__ n_tiles, int* __restrict__ tile_e,
                           int* __restrict__ tile_r0) {
  if (threadIdx.x == 0 && blockIdx.x == 0) {
    int off = 0; float aux = 0.f; int nt = 0;
    for (int e = 0; e < E_NUM; ++e) {
      offsets[e] = off; off += counts[e];
      aux += ((float)counts[e] / (float)(T_TOK * 2)) * (probs_sum[e] / (float)T_TOK);
      for (int r0 = 0; r0 < counts[e]; r0 += 128) {
        tile_e[nt] = e; tile_r0[nt] = r0; ++nt;
      }
    }
    *n_tiles = nt;
    *loss_out = (float)E_NUM * aux * 0.01f + 0.001f * (*z_sum / (float)T_TOK);
  }
}

// ---------------- scatter tokens to expert slots ----------------
__global__ __launch_bounds__(256) void k_scatter(
    const int* __restrict__ tok_e, const float* __restrict__ tok_w,
    const int* __restrict__ offsets, int* __restrict__ fill,
    int* __restrict__ rows, float* __restrict__ wgt) {
  int t = blockIdx.x * 256 + threadIdx.x;
#pragma unroll
  for (int k = 0; k < 2; ++k) {
    int e = tok_e[t * 2 + k];
    int s = offsets[e] + atomicAdd(&fill[e], 1);
    rows[s] = t;
    wgt[s] = tok_w[t * 2 + k];
  }
}

// ---------------- GEMM1: gate+up + SwiGLU -> h (bf16) ----------------
// grid = NTS x 64 (ct over I/64); XCD-chunked, ct-major swizzle.
__global__ __launch_bounds__(256, 2) void k_gemm1(
    const unsigned short* __restrict__ xb,
    const unsigned short* __restrict__ gwb, const unsigned short* __restrict__ uwb,
    const int* __restrict__ counts, const int* __restrict__ offsets,
    const int* __restrict__ rows, unsigned short* __restrict__ h,
    const int* __restrict__ n_tiles, const int* __restrict__ tile_e,
    const int* __restrict__ tile_r0) {
  const int total = NTS * (I_DIM / 64);
  const int chunk = total >> 3;
  int orig = blockIdx.y * NTS + blockIdx.x;
  int L = (orig & 7) * chunk + (orig >> 3);
  int ct = L / NTS;
  int bxt = L - ct * NTS;
  if (bxt >= *n_tiles) return;
  int e = tile_e[bxt];
  int r0 = tile_r0[bxt];
  int Te = counts[e];
  int base = offsets[e];

  __shared__ __align__(16) unsigned short sA[128 * 64];
  __shared__ __align__(16) unsigned short sG[64 * 64];
  __shared__ __align__(16) unsigned short sU[64 * 64];

  int tid = threadIdx.x, lane = tid & 63, wv = tid >> 6;
  int wr = wv >> 1, wc = wv & 1;

  // pre-swizzled global granule so linear LDS write == swizzled content
  int gsg = ((lane & 7) ^ (lane >> 3)) * 8;

  const unsigned short* a_src[4];
  unsigned short* a_dst[4];
#pragma unroll
  for (int i = 0; i < 4; ++i) {
    int r = 32 * wv + 8 * i + (lane >> 3);
    int lr = r0 + r; if (lr >= Te) lr = Te - 1;
    a_src[i] = xb + (size_t)rows[base + lr] * H + gsg;
    a_dst[i] = sA + (32 * wv + 8 * i) * 64;
  }
  const unsigned short* g_src[2]; const unsigned short* u_src[2];
  unsigned short* g_dst[2]; unsigned short* u_dst[2];
#pragma unroll
  for (int j = 0; j < 2; ++j) {
    int r = 16 * wv + 8 * j + (lane >> 3);
    size_t wrow = ((size_t)e * I_DIM + (size_t)ct * 64 + r) * H + gsg;
    g_src[j] = gwb + wrow;
    u_src[j] = uwb + wrow;
    g_dst[j] = sG + (16 * wv + 8 * j) * 64;
    u_dst[j] = sU + (16 * wv + 8 * j) * 64;
  }

  f32x4 accg[4][2], accu[4][2];
#pragma unroll
  for (int m = 0; m < 4; ++m)
#pragma unroll
    for (int n = 0; n < 2; ++n) { accg[m][n] = (f32x4)0.f; accu[m][n] = (f32x4)0.f; }

  for (int k0 = 0; k0 < H; k0 += 64) {
#pragma unroll
    for (int i = 0; i < 4; ++i) gload16(a_src[i] + k0, a_dst[i]);
#pragma unroll
    for (int j = 0; j < 2; ++j) gload16(g_src[j] + k0, g_dst[j]);
#pragma unroll
    for (int j = 0; j < 2; ++j) gload16(u_src[j] + k0, u_dst[j]);
    __syncthreads();

#pragma unroll
    for (int kk = 0; kk < 2; ++kk) {
      bf16x8 af[4], gf[2], uf[2];
#pragma unroll
      for (int m = 0; m < 4; ++m) {
        int r = 64 * wr + m * 16 + (lane & 15);
        int g = (kk * 4 + (lane >> 4)) ^ (r & 7);
        af[m] = *(const bf16x8*)&sA[r * 64 + g * 8];
      }
#pragma unroll
      for (int n = 0; n < 2; ++n) {
        int r = 32 * wc + n * 16 + (lane & 15);
        int g = (kk * 4 + (lane >> 4)) ^ (r & 7);
        gf[n] = *(const bf16x8*)&sG[r * 64 + g * 8];
        uf[n] = *(const bf16x8*)&sU[r * 64 + g * 8];
      }
#pragma unroll
      for (int m = 0; m < 4; ++m)
#pragma unroll
        for (int n = 0; n < 2; ++n) {
          accg[m][n] = __builtin_amdgcn_mfma_f32_16x16x32_bf16(af[m], gf[n], accg[m][n], 0, 0, 0);
          accu[m][n] = __builtin_amdgcn_mfma_f32_16x16x32_bf16(af[m], uf[n], accu[m][n], 0, 0, 0);
        }
    }
    __syncthreads();
  }

  int cbase = ct * 64 + wc * 32;
#pragma unroll
  for (int m = 0; m < 4; ++m)
#pragma unroll
    for (int j = 0; j < 4; ++j) {
      int lrow = 64 * wr + m * 16 + (lane >> 4) * 4 + j;
      if (r0 + lrow < Te) {
        unsigned short* hrow = h + (size_t)(base + r0 + lrow) * I_DIM + cbase + (lane & 15);
#pragma unroll
        for (int n = 0; n < 2; ++n) {
          float g = accg[m][n][j], u = accu[m][n][j];
          float hv = g / (1.f + expf(-g)) * u;
          hrow[n * 16] = f2bf(hv);
        }
      }
    }
}

// ---------------- GEMM2: down + weighted combine ----------------
// grid = NTS x 16 (ct over H/128); block tile 128 x 128, wave 64x64, acc 4x4.
__global__ __launch_bounds__(256, 2) void k_gemm2(
    const unsigned short* __restrict__ h, const unsigned short* __restrict__ dwb,
    const int* __restrict__ counts, const int* __restrict__ offsets,
    const int* __restrict__ rows, const float* __restrict__ wgt,
    float* __restrict__ out,
    const int* __restrict__ n_tiles, const int* __restrict__ tile_e,
    const int* __restrict__ tile_r0) {
  const int total = NTS * (H / 128);
  const int chunk = total >> 3;
  int orig = blockIdx.y * NTS + blockIdx.x;
  int L = (orig & 7) * chunk + (orig >> 3);
  int ct = L / NTS;
  int bxt = L - ct * NTS;
  if (bxt >= *n_tiles) return;
  int e = tile_e[bxt];
  int r0 = tile_r0[bxt];
  int Te = counts[e];
  int base = offsets[e];

  __shared__ __align__(16) unsigned short sA[128 * 64];
  __shared__ __align__(16) unsigned short sB[128 * 64];

  int tid = threadIdx.x, lane = tid & 63, wv = tid >> 6;
  int wr = wv >> 1, wc = wv & 1;

  int gsg = ((lane & 7) ^ (lane >> 3)) * 8;

  const unsigned short* a_src[4];
  unsigned short* a_dst[4];
#pragma unroll
  for (int i = 0; i < 4; ++i) {
    int r = 32 * wv + 8 * i + (lane >> 3);
    int lr = r0 + r; if (lr >= Te) lr = Te - 1;
    a_src[i] = h + (size_t)(base + lr) * I_DIM + gsg;
    a_dst[i] = sA + (32 * wv + 8 * i) * 64;
  }
  const unsigned short* b_src[4];
  unsigned short* b_dst[4];
#pragma unroll
  for (int i = 0; i < 4; ++i) {
    int r = 32 * wv + 8 * i + (lane >> 3);
    b_src[i] = dwb + ((size_t)e * H + (size_t)ct * 128 + r) * I_DIM + gsg;
    b_dst[i] = sB + (32 * wv + 8 * i) * 64;
  }

  f32x4 acc[4][4];
#pragma unroll
  for (int m = 0; m < 4; ++m)
#pragma unroll
    for (int n = 0; n < 4; ++n) acc[m][n] = (f32x4)0.f;

  for (int k0 = 0; k0 < I_DIM; k0 += 64) {
#pragma unroll
    for (int i = 0; i < 4; ++i) gload16(a_src[i] + k0, a_dst[i]);
#pragma unroll
    for (int i = 0; i < 4; ++i) gload16(b_src[i] + k0, b_dst[i]);
    __syncthreads();

#pragma unroll
    for (int kk = 0; kk < 2; ++kk) {
      bf16x8 af[4], bf[4];
#pragma unroll
      for (int m = 0; m < 4; ++m) {
        int r = 64 * wr + m * 16 + (lane & 15);
        int g = (kk * 4 + (lane >> 4)) ^ (r & 7);
        af[m] = *(const bf16x8*)&sA[r * 64 + g * 8];
      }
#pragma unroll
      for (int n = 0; n < 4; ++n) {
        int r = 64 * wc + n * 16 + (lane & 15);
        int g = (kk * 4 + (lane >> 4)) ^ (r & 7);
        bf[n] = *(const bf16x8*)&sB[r * 64 + g * 8];
      }
#pragma unroll
      for (int m = 0; m < 4; ++m)
#pragma unroll
        for (int n = 0; n < 4; ++n)
          acc[m][n] = __builtin_amdgcn_mfma_f32_16x16x32_bf16(af[m], bf[n], acc[m][n], 0, 0, 0);
    }
    __syncthreads();
  }

  int cbase = ct * 128 + wc * 64;
#pragma unroll
  for (int m = 0; m < 4; ++m)
#pragma unroll
    for (int j = 0; j < 4; ++j) {
      int lrow = 64 * wr + m * 16 + (lane >> 4) * 4 + j;
      if (r0 + lrow < Te) {
        int slot = base + r0 + lrow;
        float w = wgt[slot];
        float* orow = out + (size_t)rows[slot] * H + cbase + (lane & 15);
#pragma unroll
        for (int n = 0; n < 4; ++n)
          atomicAdd(&orow[n * 16], acc[m][n][j] * w);
      }
    }
}

extern "C" void kernel_launch(void* const* d_in, const int* in_sizes, int n_in,
                              void* d_out, int out_size, void* d_ws, size_t ws_size,
                              hipStream_t stream) {
  const float* x  = (const float*)d_in[0];
  const float* rw = (const float*)d_in[1];
  const float* gw = (const float*)d_in[2];
  const float* uw = (const float*)d_in[3];
  const float* dw = (const float*)d_in[4];
  float* out = (float*)d_out;

  char* ws = (char*)d_ws;
  int*   counts    = (int*)(ws + 0);      // 8
  int*   fill      = (int*)(ws + 32);     // 8
  int*   offsets   = (int*)(ws + 64);     // 8
  float* probs_sum = (float*)(ws + 96);   // 8
  float* z_sum     = (float*)(ws + 128);  // 1
  int*   n_tiles   = (int*)(ws + 132);    // 1
  int*   tile_e    = (int*)(ws + 256);    // <=512 ints
  int*   tile_r0   = (int*)(ws + 2304);
  int*   tok_e     = (int*)(ws + 8192);
  float* tok_w     = (float*)(ws + 8192 + 65536);
  int*   rows      = (int*)(ws + 8192 + 131072);
  float* wgt       = (float*)(ws + 8192 + 196608);
  size_t off = 8192 + 262144;
  unsigned short* xb  = (unsigned short*)(ws + off); off += (size_t)T_TOK * H * 2;
  unsigned short* hb  = (unsigned short*)(ws + off); off += (size_t)SLOTS * I_DIM * 2;
  unsigned short* gwb = (unsigned short*)(ws + off); off += (size_t)E_NUM * I_DIM * H * 2;
  unsigned short* uwb = (unsigned short*)(ws + off); off += (size_t)E_NUM * I_DIM * H * 2;
  unsigned short* dwb = (unsigned short*)(ws + off); off += (size_t)E_NUM * H * I_DIM * 2;

  hipMemsetAsync(ws, 0, 256, stream);
  hipMemsetAsync(d_out, 0, (size_t)out_size * sizeof(float), stream);

  const int WN = E_NUM * I_DIM * H;  // 67.1M elements per weight tensor
  k_cvt<<<(T_TOK * H / 8) / 256, 256, 0, stream>>>(x, xb);
  k_cvt<<<(WN / 8) / 256, 256, 0, stream>>>(gw, gwb);
  k_cvt<<<(WN / 8) / 256, 256, 0, stream>>>(uw, uwb);
  k_cvt<<<(WN / 8) / 256, 256, 0, stream>>>(dw, dwb);
  k_router<<<T_TOK / 32, 256, 0, stream>>>(x, rw, tok_e, tok_w, counts, probs_sum, z_sum);
  k_finalize<<<1, 64, 0, stream>>>(counts, offsets, probs_sum, z_sum, out + (out_size - 1),
                                   n_tiles, tile_e, tile_r0);
  k_scatter<<<T_TOK / 256, 256, 0, stream>>>(tok_e, tok_w, offsets, fill, rows, wgt);
  k_gemm1<<<dim3(NTS, I_DIM / 64), 256, 0, stream>>>(xb, gwb, uwb, counts, offsets, rows, hb,
                                                     n_tiles, tile_e, tile_r0);
  k_gemm2<<<dim3(NTS, H / 128), 256, 0, stream>>>(hb, dwb, counts, offsets, rows, wgt, out,
                                                  n_tiles, tile_e, tile_r0);
}